// Round 4
// baseline (739.796 us; speedup 1.0000x reference)
//
#include <hip/hip_runtime.h>
#include <stdint.h>
#include <math.h>

#define HW    524288      // 512*1024 pixels (2^19)
#define NETA  7
#define F     68          // NPROG*LEV
#define TILE  512         // pixels per block == threads per block
#define NW    8           // waves per block

// ---------------- threefry2x32, key = (0, 42)  [jax.random.key(42)] ----------------
// jax_threefry_partitionable=True (default): counter=(0,i), bits = o0 ^ o1.
// Verified bit-exact vs np reference (absmax 0.0 rounds 0-3).
__device__ __forceinline__ uint32_t threefry_xor_k42(uint32_t x0, uint32_t x1) {
  const uint32_t ks0 = 0u;
  const uint32_t ks1 = 42u;
  const uint32_t ks2 = 0x1BD11BDAu ^ ks0 ^ ks1;
  x0 += ks0; x1 += ks1;
#define RND(r) { x0 += x1; x1 = (x1 << (r)) | (x1 >> (32 - (r))); x1 ^= x0; }
  RND(13) RND(15) RND(26) RND(6)   x0 += ks1; x1 += ks2 + 1u;
  RND(17) RND(29) RND(16) RND(24)  x0 += ks2; x1 += ks0 + 2u;
  RND(13) RND(15) RND(26) RND(6)   x0 += ks0; x1 += ks1 + 3u;
  RND(17) RND(29) RND(16) RND(24)  x0 += ks1; x1 += ks2 + 4u;
  RND(13) RND(15) RND(26) RND(6)   x0 += ks2; x1 += ks0 + 5u;
#undef RND
  return x0 ^ x1;
}

// categorical via exponential race: argmin_k [(-ln u_k)/(T[r,k]+1e-9)]
// f32 screen with hw log2; exact f64 fallback when top-2 gap ambiguous (rare).
__device__ __forceinline__ int sample_eta(int p, int r,
                                          const float* rinv32,
                                          const double* rinv64) {
  float w[NETA];
#pragma unroll
  for (int k = 0; k < NETA; k++) {
    const uint32_t bits = threefry_xor_k42(0u, (uint32_t)(7 * p + k));
    const float f = __uint_as_float((bits >> 9) | 0x3f800000u) - 1.0f;
    const float u = (f == 0.0f) ? 1.1754943508222875e-38f : f;
    w[k] = (-__log2f(u)) * rinv32[r * NETA + k];
  }
  float w1 = w[0], w2 = 3.4e38f;
  int e = 0;
#pragma unroll
  for (int k = 1; k < NETA; k++) {
    if (w[k] < w1)      { w2 = w1; w1 = w[k]; e = k; }
    else if (w[k] < w2) { w2 = w[k]; }
  }
  if (!((w2 - w1) > 3e-5f * w2)) {
    double b1 = 1e300;
    e = 0;
    for (int k = 0; k < NETA; k++) {
      const uint32_t bits = threefry_xor_k42(0u, (uint32_t)(7 * p + k));
      const float f = __uint_as_float((bits >> 9) | 0x3f800000u) - 1.0f;
      const double u = (f == 0.0f) ? (double)1.1754943508222875e-38f : (double)f;
      const double wv = -log(u) * rinv64[r * NETA + k];
      if (wv < b1) { b1 = wv; e = k; }
    }
  }
  return e;
}

// ---------------- fused kernel: sample -> block-local sort -> broadcast-W matvec ----------------
// Block = 512 threads = 512 consecutive pixels. Ballot-rank sort by expert makes
// waves ~1.75-expert-pure; masked passes handle boundaries. W pointer is based on
// the PER-LANE expert (se): addresses are uniform at runtime within a pass, so the
// TA collapses each wave-load to one L1 line (W expert = 18.5 KB, L1-resident),
// and the compiler pipelines the global_load stream deeply (vmcnt), unlike the
// shallow s_load path of round 3. x column lives in registers (launch_bounds
// without a min-waves floor -> 256-VGPR cap -> xv[68] stays resident; round 3's
// (512,4) cap made the compiler rematerialize x loads = 90% stall).
// FMA chain order: f ascending per output, bias last (bit-exact, rounds 1-3).
__global__ void __launch_bounds__(512) fused_kernel(const float* __restrict__ x,
                                                    const float* __restrict__ W,
                                                    const float* __restrict__ b,
                                                    const float* __restrict__ T,
                                                    const int* __restrict__ eta,
                                                    float* __restrict__ out) {
  __shared__ float  rinv32[NETA * NETA];
  __shared__ double rinv64[NETA * NETA];
  __shared__ int    cnt[NETA * NW];     // [expert][wave] chunk counts
  __shared__ int    tot[NETA];          // per-expert totals
  __shared__ int    sidx[TILE];         // sorted slot -> (e<<9)|local_pixel
  __shared__ float  olds[17 * TILE];    // out staging for one 17-row o-chunk (34.8 KB)

  const int tid  = threadIdx.x;
  const int lane = tid & 63;
  const int w    = tid >> 6;
  const int blkbase = blockIdx.x * TILE;

  if (tid < NETA * NETA) {
    double d = 1.0 / ((double)T[tid] + 1e-9);
    rinv64[tid] = d;
    rinv32[tid] = (float)d;
  }
  __syncthreads();

  // ---- sample (1 pixel per thread; eta_new lives only in registers) ----
  const int p = blkbase + tid;
  const int e = sample_eta(p, eta[p], rinv32, rinv64);

  // ---- ballot-rank counting sort over 7 experts ----
  int myrank = 0;
#pragma unroll
  for (int k = 0; k < NETA; k++) {
    const unsigned long long mk = __ballot(e == k);
    if (e == k) myrank = (int)__popcll(mk & ((1ull << lane) - 1ull));
    if (lane == 0) cnt[k * NW + w] = (int)__popcll(mk);
  }
  __syncthreads();
  if (tid < NETA) {
    int s = 0;
#pragma unroll
    for (int j = 0; j < NW; j++) s += cnt[tid * NW + j];
    tot[tid] = s;
  }
  __syncthreads();
  int off = myrank;
#pragma unroll
  for (int k = 0; k < NETA; k++) if (k < e) off += tot[k];
#pragma unroll
  for (int j = 0; j < NW; j++) if (j < w) off += cnt[e * NW + j];
  sidx[off] = (e << 9) | tid;
  __syncthreads();

  // ---- my sorted slot: expert nearly wave-uniform now ----
  const int v  = sidx[w * 64 + lane];
  const int se = v >> 9;
  const int lp = v & (TILE - 1);

  // full x column for my pixel, resident in VGPRs (loaded once, used 272x)
  float xv[F];
#pragma unroll
  for (int f = 0; f < F; f++) xv[f] = x[(size_t)f * HW + blkbase + lp];

  for (int oc = 0; oc < 4; oc++) {
    const int o0 = oc * 17;

    bool active = true;
    while (__any(active)) {
      const unsigned long long mm = __ballot(active);
      const int lead = (int)__ffsll(mm) - 1;
      const int e0   = __builtin_amdgcn_readfirstlane(__shfl(se, lead));
      const bool go  = active && (se == e0);
      if (go) {
        // per-lane base (runtime-uniform within the pass) -> vector broadcast loads
        const float* __restrict__ wb = W + (size_t)se * (F * F) + (size_t)o0 * F;
        const float* __restrict__ bb = b + (size_t)se * F + o0;

        // 17 outputs as 4 groups of 4 + 1; float4 W loads, chain f-ascending.
#pragma unroll
        for (int ig = 0; ig < 4; ig++) {
          const int i0 = ig * 4;
          float a0 = 0.0f, a1 = 0.0f, a2 = 0.0f, a3 = 0.0f;
#pragma unroll
          for (int f4 = 0; f4 < F / 4; f4++) {
            const float4 w0 = *reinterpret_cast<const float4*>(wb + (size_t)(i0 + 0) * F + 4 * f4);
            const float4 w1 = *reinterpret_cast<const float4*>(wb + (size_t)(i0 + 1) * F + 4 * f4);
            const float4 w2 = *reinterpret_cast<const float4*>(wb + (size_t)(i0 + 2) * F + 4 * f4);
            const float4 w3 = *reinterpret_cast<const float4*>(wb + (size_t)(i0 + 3) * F + 4 * f4);
            const float x0 = xv[4 * f4 + 0];
            const float x1 = xv[4 * f4 + 1];
            const float x2 = xv[4 * f4 + 2];
            const float x3 = xv[4 * f4 + 3];
            a0 = fmaf(w0.x, x0, a0); a0 = fmaf(w0.y, x1, a0); a0 = fmaf(w0.z, x2, a0); a0 = fmaf(w0.w, x3, a0);
            a1 = fmaf(w1.x, x0, a1); a1 = fmaf(w1.y, x1, a1); a1 = fmaf(w1.z, x2, a1); a1 = fmaf(w1.w, x3, a1);
            a2 = fmaf(w2.x, x0, a2); a2 = fmaf(w2.y, x1, a2); a2 = fmaf(w2.z, x2, a2); a2 = fmaf(w2.w, x3, a2);
            a3 = fmaf(w3.x, x0, a3); a3 = fmaf(w3.y, x1, a3); a3 = fmaf(w3.z, x2, a3); a3 = fmaf(w3.w, x3, a3);
          }
          olds[(i0 + 0) * TILE + lp] = a0 + bb[i0 + 0];
          olds[(i0 + 1) * TILE + lp] = a1 + bb[i0 + 1];
          olds[(i0 + 2) * TILE + lp] = a2 + bb[i0 + 2];
          olds[(i0 + 3) * TILE + lp] = a3 + bb[i0 + 3];
        }
        {
          float a = 0.0f;
#pragma unroll
          for (int f4 = 0; f4 < F / 4; f4++) {
            const float4 w0 = *reinterpret_cast<const float4*>(wb + (size_t)16 * F + 4 * f4);
            a = fmaf(w0.x, xv[4 * f4 + 0], a);
            a = fmaf(w0.y, xv[4 * f4 + 1], a);
            a = fmaf(w0.z, xv[4 * f4 + 2], a);
            a = fmaf(w0.w, xv[4 * f4 + 3], a);
          }
          olds[16 * TILE + lp] = a + bb[16];
        }
      }
      active = active && !go;
    }

    __syncthreads();
    // coalesced flush of 17 completed rows
#pragma unroll
    for (int i = 0; i < 17; i++)
      out[(size_t)(o0 + i) * HW + blkbase + tid] = olds[i * TILE + tid];
    __syncthreads();
  }
}

extern "C" void kernel_launch(void* const* d_in, const int* in_sizes, int n_in,
                              void* d_out, int out_size, void* d_ws, size_t ws_size,
                              hipStream_t stream) {
  const float* x   = (const float*)d_in[0];
  const float* W   = (const float*)d_in[1];
  const float* b   = (const float*)d_in[2];
  const float* T   = (const float*)d_in[3];
  const int*   eta = (const int*)d_in[4];
  float* out = (float*)d_out;

  fused_kernel<<<HW / TILE, TILE, 0, stream>>>(x, W, b, T, eta, out);
}